// Round 1
// baseline (322.056 us; speedup 1.0000x reference)
//
#include <hip/hip_runtime.h>
#include <hip/hip_cooperative_groups.h>

namespace cg = cooperative_groups;

#define BATCH 16
#define T_LEN 2048
#define E_DIM 768
#define E4 (E_DIM / 4)          // 192 float4 per row
#define N_SENT 32
#define S_LEN 64
#define NCHUNK 32               // T chunks of 64 rows
#define NBLK (BATCH * NCHUNK)   // 512 blocks = 2 per CU -> co-resident

__device__ __forceinline__ void add4(float4& a, const float4 v) {
    a.x += v.x; a.y += v.y; a.z += v.z; a.w += v.w;
}

// Single cooperative kernel: phase A (pool partials) -> grid.sync ->
// phase B (mean + tiny matmul + indices, blocks 0..15) -> grid.sync ->
// phase C (gather/copy rows).
// 512 blocks x 256 threads (4 waves). Block g owns (b = g>>5, chunk/sentence = g&31):
// phase A pools rows [tc*64, tc*64+64) of batch b; phase C writes sentence tc of
// batch b, whose source rows are ~the same region -> per-XCD L2 reuse.
__global__ __launch_bounds__(256, 2) void fused_all(
    const float4* __restrict__ in4,
    const float*  __restrict__ W,
    const float*  __restrict__ bias,
    float4* __restrict__ partial4,
    int* __restrict__ sidx,
    int* __restrict__ eidx,
    float4* __restrict__ out4)
{
    cg::grid_group grid = cg::this_grid();

    const int tid  = threadIdx.x;
    const int lane = tid & 63;
    const int q    = tid >> 6;          // wave id 0..3
    const int g    = blockIdx.x;
    const int b    = g >> 5;            // batch
    const int tc   = g & 31;            // row-chunk == sentence id

    __shared__ float4 red[4][E4];       // 12 KB cross-wave reduce buffer

    // ---------------- Phase A: partial column sums over 64 rows ----------------
    {
        const float4* base = in4 + ((size_t)b * T_LEN + (size_t)tc * 64) * E4;
        float4 s0 = make_float4(0.f,0.f,0.f,0.f), s1 = s0, s2 = s0;
        // wave q streams rows [q*16, q*16+16); each row = 3 chunks of 64 float4
        #pragma unroll 4
        for (int k = 0; k < 16; ++k) {
            const float4* p = base + (size_t)(q * 16 + k) * E4 + lane;
            add4(s0, p[0]);
            add4(s1, p[64]);
            add4(s2, p[128]);
        }
        red[q][lane]       = s0;
        red[q][lane + 64]  = s1;
        red[q][lane + 128] = s2;
    }
    __syncthreads();
    if (tid < E4) {
        float4 t = red[0][tid];
        add4(t, red[1][tid]); add4(t, red[2][tid]); add4(t, red[3][tid]);
        partial4[((size_t)tc * BATCH + b) * E4 + tid] = t;
    }
    grid.sync();

    // ---------------- Phase B: mean + pooled@W + index computation -------------
    if (g < BATCH) {                    // block g handles batch g
        __shared__ float pooled[E_DIM];
        __shared__ float colsum[4][2 * N_SENT];
        __shared__ int   offi[2 * N_SENT];

        if (tid < E4) {
            float4 s = make_float4(0.f,0.f,0.f,0.f);
            #pragma unroll
            for (int pc = 0; pc < NCHUNK; ++pc)
                add4(s, partial4[((size_t)pc * BATCH + g) * E4 + tid]);
            const float inv = 1.0f / (float)T_LEN;
            ((float4*)pooled)[tid] = make_float4(s.x*inv, s.y*inv, s.z*inv, s.w*inv);
        }
        __syncthreads();

        // tid -> (quarter qq, column c). Lanes share qq -> pooled reads broadcast;
        // consecutive c -> W reads coalesced (W is [768][64] row-major).
        const int c  = tid & 63;
        const int qq = tid >> 6;
        float acc = 0.f;
        const float* pb = pooled + qq * 192;
        const float* Wq = W + (size_t)qq * 192 * (2 * N_SENT) + c;
        #pragma unroll 8
        for (int e = 0; e < 192; ++e) acc += pb[e] * Wq[(size_t)e * (2 * N_SENT)];
        colsum[qq][c] = acc;
        __syncthreads();

        if (tid < 2 * N_SENT) {
            float o = bias[tid] + colsum[0][tid] + colsum[1][tid]
                                + colsum[2][tid] + colsum[3][tid];
            float cl = fminf(fmaxf(o, 0.f), (float)(S_LEN - 1));
            offi[tid] = (int)cl;        // nonneg -> trunc == floor == astype(int32)
        }
        __syncthreads();

        if (tid < N_SENT) {
            const int so   = offi[tid];
            const int eo   = offi[N_SENT + tid];
            const int bse  = tid * S_LEN;
            int si = min(bse + so, T_LEN - S_LEN);            // clip(base+so,0,T-L)
            int ei = min(max(bse + S_LEN + eo, si), T_LEN);   // clip(base+L+eo,si,T)
            sidx[g * N_SENT + tid] = si;
            eidx[g * N_SENT + tid] = ei;
        }
    }
    grid.sync();

    // ---------------- Phase C: gather rows (or zeros) --------------------------
    {
        const int si  = sidx[b * N_SENT + tc];
        const int ei  = eidx[b * N_SENT + tc];
        const int len = ei - si;
        const float4* src = in4  + ((size_t)b * T_LEN + si) * E4 + lane;
        float4*       dst = out4 + (((size_t)b * N_SENT + tc) * S_LEN) * E4 + lane;
        const float4 z = make_float4(0.f,0.f,0.f,0.f);
        // wave q writes rows [q*16, q*16+16); j wave-uniform -> no divergence
        #pragma unroll 2
        for (int k = 0; k < 16; ++k) {
            const int j = q * 16 + k;
            float4 v0 = z, v1 = z, v2 = z;
            if (j < len) {
                const float4* sp = src + (size_t)j * E4;   // si+j <= 2047 always
                v0 = sp[0]; v1 = sp[64]; v2 = sp[128];
            }
            float4* dp = dst + (size_t)j * E4;
            dp[0] = v0; dp[64] = v1; dp[128] = v2;         // always write (poisoned)
        }
    }
}

extern "C" void kernel_launch(void* const* d_in, const int* in_sizes, int n_in,
                              void* d_out, int out_size, void* d_ws, size_t ws_size,
                              hipStream_t stream) {
    const float4* in4  = (const float4*)d_in[0];  // [16, 2048, 768]
    const float*  W    = (const float*)d_in[1];   // [768, 64]
    const float*  bias = (const float*)d_in[2];   // [64]
    float4* out4 = (float4*)d_out;                // [16, 32, 64, 768]

    float4* partial4 = (float4*)d_ws;             // NCHUNK*BATCH*E4 float4 = 1.5 MB
    int* sidx = (int*)((char*)d_ws + (size_t)NCHUNK * BATCH * E4 * sizeof(float4));
    int* eidx = sidx + BATCH * N_SENT;

    void* args[] = { (void*)&in4, (void*)&W, (void*)&bias, (void*)&partial4,
                     (void*)&sidx, (void*)&eidx, (void*)&out4 };
    hipLaunchCooperativeKernel((const void*)fused_all, dim3(NBLK), dim3(256),
                               args, 0, stream);
}

// Round 2
// 295.572 us; speedup vs baseline: 1.0896x; 1.0896x over previous
//
#include <hip/hip_runtime.h>

#define BATCH 16
#define T_LEN 2048
#define E_DIM 768
#define E4 (E_DIM / 4)          // 192 float4 per row
#define N_SENT 32
#define S_LEN 64
#define NCHUNK 32               // T chunks of 64 rows
#define NBLK (BATCH * NCHUNK)   // 512 blocks = 2 per CU
#define CNT_STRIDE 16           // ints -> 64 B per batch counter (own cacheline)

__device__ __forceinline__ void add4(float4& a, const float4 v) {
    a.x += v.x; a.y += v.y; a.z += v.z; a.w += v.w;
}

// Single kernel, per-batch dependency instead of grid.sync:
//  A) block (b,tc) pools rows [tc*64, tc*64+64) of batch b -> partial4
//     -> threadfence -> atomicAdd on padded per-batch counter
//  B) last-arriving block of batch b: mean + pooled@W + indices; publishes each
//     sentence's (si,ei) as ONE packed word (marker bit 31 | si<<12 | ei) via
//     device-scope atomic store. Payload rides in the flag -> no consumer fence.
//  C) every block spins (s_sleep) on its own sentence's word, then gathers.
// Producers never wait before completing A -> no deadlock; cooperative launch
// guarantees co-residency regardless.
__global__ __launch_bounds__(256, 2) void fused_all(
    const float4* __restrict__ in4,
    const float*  __restrict__ W,
    const float*  __restrict__ bias,
    float4* __restrict__ partial4,
    int*    __restrict__ cnt,
    unsigned int* __restrict__ packed,
    float4* __restrict__ out4)
{
    const int tid  = threadIdx.x;
    const int lane = tid & 63;
    const int q    = tid >> 6;          // wave id 0..3
    const int g    = blockIdx.x;
    const int b    = g >> 5;            // batch
    const int tc   = g & 31;            // row-chunk == sentence id

    __shared__ float4 red[4][E4];       // 12 KB cross-wave reduce buffer
    __shared__ int amLast;
    __shared__ unsigned int myw;

    // ---------------- Phase A: partial column sums over 64 rows ----------------
    {
        const float4* base = in4 + ((size_t)b * T_LEN + (size_t)tc * 64) * E4;
        float4 s0 = make_float4(0.f,0.f,0.f,0.f), s1 = s0, s2 = s0;
        #pragma unroll 4
        for (int k = 0; k < 16; ++k) {
            const float4* p = base + (size_t)(q * 16 + k) * E4 + lane;
            add4(s0, p[0]);
            add4(s1, p[64]);
            add4(s2, p[128]);
        }
        red[q][lane]       = s0;
        red[q][lane + 64]  = s1;
        red[q][lane + 128] = s2;
    }
    __syncthreads();
    if (tid < E4) {
        float4 t = red[0][tid];
        add4(t, red[1][tid]); add4(t, red[2][tid]); add4(t, red[3][tid]);
        partial4[((size_t)tc * BATCH + b) * E4 + tid] = t;
    }
    __threadfence();            // each writer releases its own partial stores
    __syncthreads();            // counter bump happens-after all fences
    if (tid == 0) {
        int old = atomicAdd(&cnt[b * CNT_STRIDE], 1);   // padded line per batch
        amLast = (old == NCHUNK - 1) ? 1 : 0;
    }
    __syncthreads();

    // ---------------- Phase B: last block per batch computes indices -----------
    if (amLast) {
        __threadfence();        // acquire side: fresh view of partial4
        __shared__ float pooled[E_DIM];
        __shared__ float colsum[4][2 * N_SENT];
        __shared__ int   offi[2 * N_SENT];

        if (tid < E4) {
            float4 s = make_float4(0.f,0.f,0.f,0.f);
            #pragma unroll
            for (int pc = 0; pc < NCHUNK; ++pc)
                add4(s, partial4[((size_t)pc * BATCH + b) * E4 + tid]);
            const float inv = 1.0f / (float)T_LEN;
            ((float4*)pooled)[tid] = make_float4(s.x*inv, s.y*inv, s.z*inv, s.w*inv);
        }
        __syncthreads();

        // lanes share qq -> pooled broadcast; consecutive c -> W coalesced
        const int c  = tid & 63;
        const int qq = tid >> 6;
        float acc = 0.f;
        const float* pb = pooled + qq * 192;
        const float* Wq = W + (size_t)qq * 192 * (2 * N_SENT) + c;
        #pragma unroll 8
        for (int e = 0; e < 192; ++e) acc += pb[e] * Wq[(size_t)e * (2 * N_SENT)];
        colsum[qq][c] = acc;
        __syncthreads();

        if (tid < 2 * N_SENT) {
            float o = bias[tid] + colsum[0][tid] + colsum[1][tid]
                                + colsum[2][tid] + colsum[3][tid];
            float cl = fminf(fmaxf(o, 0.f), (float)(S_LEN - 1));
            offi[tid] = (int)cl;        // nonneg -> trunc == floor == astype(int32)
        }
        __syncthreads();

        if (tid < N_SENT) {
            const int so  = offi[tid];
            const int eo  = offi[N_SENT + tid];
            const int bse = tid * S_LEN;
            int si = min(bse + so, T_LEN - S_LEN);            // <= 1984, 11 bits
            int ei = min(max(bse + S_LEN + eo, si), T_LEN);   // <= 2048, 12 bits
            unsigned wrd = 0x80000000u | ((unsigned)si << 12) | (unsigned)ei;
            __hip_atomic_store(&packed[b * N_SENT + tid], wrd,
                               __ATOMIC_RELAXED, __HIP_MEMORY_SCOPE_AGENT);
        }
    }

    // ---------------- Phase C: wait for own sentence, then gather --------------
    if (tid == 0) {
        unsigned int w;
        while (!((w = __hip_atomic_load(&packed[g], __ATOMIC_RELAXED,
                                        __HIP_MEMORY_SCOPE_AGENT)) & 0x80000000u))
            __builtin_amdgcn_s_sleep(8);
        myw = w;
    }
    __syncthreads();

    const unsigned int w = myw;
    const int si  = (int)((w >> 12) & 0x7FFu);
    const int ei  = (int)(w & 0xFFFu);
    const int len = ei - si;
    const float4* src = in4  + ((size_t)b * T_LEN + si) * E4 + lane;
    float4*       dst = out4 + ((size_t)g * S_LEN) * E4 + lane;
    const float4 z = make_float4(0.f,0.f,0.f,0.f);
    // wave q writes rows [q*16, q*16+16); j wave-uniform -> no divergence
    #pragma unroll 2
    for (int k = 0; k < 16; ++k) {
        const int j = q * 16 + k;
        float4 v0 = z, v1 = z, v2 = z;
        if (j < len) {
            const float4* sp = src + (size_t)j * E4;   // si+j <= 2047 always
            v0 = sp[0]; v1 = sp[64]; v2 = sp[128];
        }
        float4* dp = dst + (size_t)j * E4;
        dp[0] = v0; dp[64] = v1; dp[128] = v2;         // always write (poisoned)
    }
}

extern "C" void kernel_launch(void* const* d_in, const int* in_sizes, int n_in,
                              void* d_out, int out_size, void* d_ws, size_t ws_size,
                              hipStream_t stream) {
    const float4* in4  = (const float4*)d_in[0];  // [16, 2048, 768]
    const float*  W    = (const float*)d_in[1];   // [768, 64]
    const float*  bias = (const float*)d_in[2];   // [64]
    float4* out4 = (float4*)d_out;                // [16, 32, 64, 768]

    const size_t partialBytes = (size_t)NCHUNK * BATCH * E4 * sizeof(float4); // 1.5 MB
    float4* partial4 = (float4*)d_ws;
    int* cnt = (int*)((char*)d_ws + partialBytes);
    unsigned int* packed = (unsigned int*)(cnt + BATCH * CNT_STRIDE);

    // workspace is poisoned each iteration: zero counters + flag words (3 KB)
    hipMemsetAsync((char*)d_ws + partialBytes, 0,
                   (size_t)BATCH * CNT_STRIDE * sizeof(int) + (size_t)NBLK * sizeof(unsigned int),
                   stream);

    void* args[] = { (void*)&in4, (void*)&W, (void*)&bias, (void*)&partial4,
                     (void*)&cnt, (void*)&packed, (void*)&out4 };
    hipLaunchCooperativeKernel((const void*)fused_all, dim3(NBLK), dim3(256),
                               args, 0, stream);
}

// Round 4
// 208.035 us; speedup vs baseline: 1.5481x; 1.4208x over previous
//
#include <hip/hip_runtime.h>

#define BATCH 16
#define T_LEN 2048
#define E_DIM 768
#define E4 (E_DIM / 4)        // 192 float4 per row
#define N_SENT 32
#define S_LEN 64
#define NCHUNK 64             // T chunks of 32 rows (4 blocks/CU for latency hiding)
#define ROWS_PER_CHUNK (T_LEN / NCHUNK)   // 32

typedef float nf4 __attribute__((ext_vector_type(4)));   // native vec for NT builtins

// -------- Kernel 1: partial column sums over T, float4-vectorized --------
// grid (BATCH, NCHUNK), block 192 (3 waves). Each block sums 32 rows of one batch.
// 1024 blocks = 4/CU = 12 waves/CU; unroll 8 keeps 8 16B loads in flight per lane.
__global__ void pool_partial(const float4* __restrict__ in4, float4* __restrict__ partial4) {
    const int tx = threadIdx.x;            // float4 index within row
    const int b  = blockIdx.x;
    const int tc = blockIdx.y;
    const float4* p = in4 + ((size_t)b * T_LEN + (size_t)tc * ROWS_PER_CHUNK) * E4 + tx;
    float4 s = make_float4(0.f, 0.f, 0.f, 0.f);
#pragma unroll 8
    for (int t = 0; t < ROWS_PER_CHUNK; ++t) {
        float4 v = p[(size_t)t * E4];
        s.x += v.x; s.y += v.y; s.z += v.z; s.w += v.w;
    }
    partial4[((size_t)tc * BATCH + b) * E4 + tx] = s;
}

// -------- Kernel 2: finish mean, tiny matmul, index computation --------
// grid BATCH blocks, 256 threads each. Phase 1: reduce NCHUNK partials -> pooled row
// (LDS). Phase 2: offsets = pooled @ W + bias, 64 cols x 4 e-quarters across threads.
// Phase 3: clip/truncate -> start/end indices.
__global__ void compute_idx(const float4* __restrict__ partial4,
                            const float* __restrict__ W,
                            const float* __restrict__ bias,
                            int* __restrict__ sidx, int* __restrict__ eidx) {
    __shared__ float pooled[E_DIM];
    __shared__ float colsum[4][2 * N_SENT];
    __shared__ int   offi[2 * N_SENT];
    const int b   = blockIdx.x;
    const int tid = threadIdx.x;

    if (tid < E4) {
        float4 s = make_float4(0.f, 0.f, 0.f, 0.f);
#pragma unroll 8
        for (int tc = 0; tc < NCHUNK; ++tc) {
            float4 v = partial4[((size_t)tc * BATCH + b) * E4 + tid];
            s.x += v.x; s.y += v.y; s.z += v.z; s.w += v.w;
        }
        const float inv = 1.0f / (float)T_LEN;
        ((float4*)pooled)[tid] = make_float4(s.x * inv, s.y * inv, s.z * inv, s.w * inv);
    }
    __syncthreads();

    // tid -> (quarter q, column c). Lanes share q -> pooled reads broadcast;
    // consecutive c -> W reads coalesced (W is [768][64] row-major).
    const int c = tid & 63;
    const int q = tid >> 6;
    float acc = 0.f;
    const float* pb = pooled + q * 192;
    const float* Wq = W + (size_t)q * 192 * (2 * N_SENT) + c;
#pragma unroll 8
    for (int e = 0; e < 192; ++e) acc += pb[e] * Wq[(size_t)e * (2 * N_SENT)];
    colsum[q][c] = acc;
    __syncthreads();

    if (tid < 2 * N_SENT) {
        float o = bias[tid] + colsum[0][tid] + colsum[1][tid] + colsum[2][tid] + colsum[3][tid];
        // clip to [0, 63] then truncate (nonneg -> floor), matching astype(int32)
        float cl = fminf(fmaxf(o, 0.f), (float)(S_LEN - 1));
        offi[tid] = (int)cl;
    }
    __syncthreads();

    if (tid < N_SENT) {
        const int so   = offi[tid];
        const int eo   = offi[N_SENT + tid];
        const int base = tid * S_LEN;
        int si = min(base + so, T_LEN - S_LEN);            // clip(base+so, 0, T-L), so>=0
        int ei = min(max(base + S_LEN + eo, si), T_LEN);   // clip(base+L+eo, si, T)
        sidx[b * N_SENT + tid] = si;
        eidx[b * N_SENT + tid] = ei;
    }
}

// -------- Kernel 3: gather rows (or zeros) --------
// grid = B*S*2 = 1024 blocks x 256 threads (4 waves). Block owns half a sentence
// (32 rows); wave q copies rows [q*8, q*8+8), 3 float4 per lane per row -> 24
// independent load/store pairs per lane (unroll 4 = 12 loads in flight).
// si/ei are block-uniform -> scalar loads. Output stores are non-temporal:
// write-once data bypasses L2, keeping input resident for the gather reads.
__global__ __launch_bounds__(256) void gather_rows(const float4* __restrict__ in4,
                                                   const int* __restrict__ sidx,
                                                   const int* __restrict__ eidx,
                                                   float4* __restrict__ out4) {
    const int blk  = blockIdx.x;
    const int half = blk & 1;              // which 32-row half of the sentence
    const int s    = (blk >> 1) & (N_SENT - 1);
    const int b    = blk >> 6;
    const int lane = threadIdx.x & 63;
    const int q    = threadIdx.x >> 6;     // wave id 0..3

    const int si  = sidx[b * N_SENT + s];
    const int ei  = eidx[b * N_SENT + s];
    const int len = ei - si;

    const float4* src = in4  + ((size_t)b * T_LEN + si) * E4 + lane;
    float4*       dst = out4 + (((size_t)b * N_SENT + s) * S_LEN) * E4 + lane;
    const float4 z = make_float4(0.f, 0.f, 0.f, 0.f);

#pragma unroll 4
    for (int k = 0; k < 8; ++k) {
        const int j = half * 32 + q * 8 + k;   // row within sentence, wave-uniform
        float4 v0 = z, v1 = z, v2 = z;
        if (j < len) {                          // si+j <= 2047 always (ei <= T)
            const float4* sp = src + (size_t)j * E4;
            v0 = sp[0]; v1 = sp[64]; v2 = sp[128];
        }
        nf4* dp = (nf4*)(dst + (size_t)j * E4);
        __builtin_nontemporal_store(*(const nf4*)&v0, dp);        // always write (poisoned)
        __builtin_nontemporal_store(*(const nf4*)&v1, dp + 64);
        __builtin_nontemporal_store(*(const nf4*)&v2, dp + 128);
    }
}

extern "C" void kernel_launch(void* const* d_in, const int* in_sizes, int n_in,
                              void* d_out, int out_size, void* d_ws, size_t ws_size,
                              hipStream_t stream) {
    const float4* in4 = (const float4*)d_in[0];  // [16, 2048, 768]
    const float*  W   = (const float*)d_in[1];   // [768, 64]
    const float*  bias= (const float*)d_in[2];   // [64]
    float4* out4 = (float4*)d_out;               // [16, 32, 64, 768]

    float4* partial4 = (float4*)d_ws;            // NCHUNK*BATCH*E4 float4 = 3 MB
    int* sidx = (int*)((char*)d_ws + (size_t)NCHUNK * BATCH * E4 * sizeof(float4));
    int* eidx = sidx + BATCH * N_SENT;

    pool_partial<<<dim3(BATCH, NCHUNK), 192, 0, stream>>>(in4, partial4);
    compute_idx<<<BATCH, 256, 0, stream>>>(partial4, W, bias, sidx, eidx);
    gather_rows<<<dim3(BATCH * N_SENT * 2), 256, 0, stream>>>(in4, sidx, eidx, out4);
}